// Round 7
// baseline (248.958 us; speedup 1.0000x reference)
//
#include <hip/hip_runtime.h>
#include <hip/hip_bf16.h>

// Dilate = 5x5 per-channel max filter, SAME padding, (64,384,384,3) f32.
// ROW-STREAMING: each wave owns FULL image rows and streams downward, so its
// DRAM walk is sequential (copy-like) instead of 4.6KB-strided columns.
//   Lane l covers f4-col 60k-2+l for chunks k=0..4 (chunks overlap 2 lanes
//   each side for the horizontal shuffle halo; lanes 2..61 store).
//   Per input row: 5 contiguous wave-loads sweeping the 4.6 KB row; hmax via
//   cross-lane __shfl per chunk; vmax via 5-deep register ring per chunk;
//   5 masked float4 stores per output row (also a sequential sweep).
//   RB=8 output rows/wave (13 input rows). grid = 64 img x 12 groups = 768
//   blocks = exactly 3 blocks/CU (12 waves/CU), perfectly balanced.

#define Bn 64
#define H 384
#define ROWBYTES 4608        // 1152 floats * 4 B
#define WF4 288              // float4s per row
#define RB 8                 // output rows per wave
#define NCH 5                // column chunks per row (5*60 = 300 >= 288)
#define SOUT 60              // output f4 cols per chunk
#define GRPS 12              // band-groups per image: 12 * 4 waves * RB = 384
#define NEGINF (-3.402823466e+38f)

__device__ __forceinline__ float4 max4(float4 a, float4 b) {
  return make_float4(fmaxf(a.x, b.x), fmaxf(a.y, b.y),
                     fmaxf(a.z, b.z), fmaxf(a.w, b.w));
}
__device__ __forceinline__ float4 shflup4(float4 v, int d) {
  return make_float4(__shfl_up(v.x, d), __shfl_up(v.y, d),
                     __shfl_up(v.z, d), __shfl_up(v.w, d));
}
__device__ __forceinline__ float4 shfldn4(float4 v, int d) {
  return make_float4(__shfl_down(v.x, d), __shfl_down(v.y, d),
                     __shfl_down(v.z, d), __shfl_down(v.w, d));
}

__global__ __launch_bounds__(256, 3) void dilate5_kernel(
    const float* __restrict__ in, float* __restrict__ out) {
  const int wv = threadIdx.x >> 6;
  const int lane = threadIdx.x & 63;
  int t = blockIdx.x;
  const int grp = t % GRPS; t /= GRPS;
  const int b = t;
  const int row0 = (grp * 4 + wv) * RB;

  const char* __restrict__ imgb = (const char*)in + (size_t)b * H * ROWBYTES;
  char* __restrict__ outb = (char*)out + (size_t)b * H * ROWBYTES;

  int coff[NCH];
  bool cval[NCH], smask[NCH];
#pragma unroll
  for (int k = 0; k < NCH; ++k) {
    const int col = SOUT * k - 2 + lane;          // owned f4 col (may be OOB)
    cval[k] = (col >= 0) && (col < WF4);
    const int ccl = col < 0 ? 0 : (col >= WF4 ? WF4 - 1 : col);
    coff[k] = ccl * 16;
    smask[k] = (lane >= 2) && (lane < 62) && (col < WF4);
  }
  const float4 ninf = make_float4(NEGINF, NEGINF, NEGINF, NEGINF);

  // load one full image row: 5 contiguous wave-loads (addresses clamped)
  auto loadrow = [&](int gh, float4* dst) {
    const int ghc = gh < 0 ? 0 : (gh > H - 1 ? H - 1 : gh);
    const char* rb = imgb + (size_t)ghc * ROWBYTES;
#pragma unroll
    for (int k = 0; k < NCH; ++k)
      dst[k] = *reinterpret_cast<const float4*>(rb + coff[k]);
  };

  // horizontal 5-max for all chunks of one row (verified tap mapping)
  auto hcombrow = [&](int gh, const float4* raw, float4* h) {
    const bool rowok = (gh >= 0) && (gh < H);
#pragma unroll
    for (int k = 0; k < NCH; ++k) {
      float4 Cv = cval[k] ? raw[k] : ninf;
      float4 A = shflup4(Cv, 2);
      float4 Bv = shflup4(Cv, 1);
      float4 D = shfldn4(Cv, 1);
      float4 E = shfldn4(Cv, 2);
      float4 r;
      r.x = fmaxf(fmaxf(fmaxf(A.z, Bv.y), fmaxf(Cv.x, Cv.w)), D.z);
      r.y = fmaxf(fmaxf(fmaxf(A.w, Bv.z), fmaxf(Cv.y, D.x)), D.w);
      r.z = fmaxf(fmaxf(fmaxf(Bv.x, Bv.w), fmaxf(Cv.z, D.y)), E.x);
      r.w = fmaxf(fmaxf(fmaxf(Bv.y, Cv.x), fmaxf(Cv.w, D.z)), E.y);
      h[k] = rowok ? r : ninf;
    }
  };

  // ---- init: issue 5 row-loads back-to-back, then hmax them ----
  float4 t0[NCH], t1[NCH], t2[NCH], t3[NCH], cur[NCH], nxt[NCH];
  loadrow(row0 - 2, t0);
  loadrow(row0 - 1, t1);
  loadrow(row0,     t2);
  loadrow(row0 + 1, t3);
  loadrow(row0 + 2, cur);

  float4 r0[NCH], r1[NCH], r2[NCH], r3[NCH], r4[NCH];
  hcombrow(row0 - 2, t0, r0);
  hcombrow(row0 - 1, t1, r1);
  hcombrow(row0,     t2, r2);
  hcombrow(row0 + 1, t3, r3);

  // ---- stream down RB output rows ----
#pragma unroll
  for (int i = 0; i < RB; ++i) {
    const int o = row0 + i;
    if (i + 1 < RB) loadrow(o + 3, nxt);   // prefetch next input row
    hcombrow(o + 2, cur, r4);
    char* orow = outb + (size_t)o * ROWBYTES;
#pragma unroll
    for (int k = 0; k < NCH; ++k) {
      float4 v = max4(max4(max4(r0[k], r1[k]), max4(r2[k], r3[k])), r4[k]);
      if (smask[k])
        *reinterpret_cast<float4*>(orow + coff[k]) = v;
    }
#pragma unroll
    for (int k = 0; k < NCH; ++k) {        // rotate ring (SSA-renamed, free)
      r0[k] = r1[k]; r1[k] = r2[k]; r2[k] = r3[k]; r3[k] = r4[k];
      cur[k] = nxt[k];
    }
  }
}

extern "C" void kernel_launch(void* const* d_in, const int* in_sizes, int n_in,
                              void* d_out, int out_size, void* d_ws, size_t ws_size,
                              hipStream_t stream) {
  const float* images = (const float*)d_in[0];
  float* out = (float*)d_out;
  const int nblocks = Bn * GRPS;   // 768 = 3 blocks per CU, fully balanced
  dilate5_kernel<<<nblocks, 256, 0, stream>>>(images, out);
}